// Round 4
// baseline (91.268 us; speedup 1.0000x reference)
//
#include <hip/hip_runtime.h>

// Quantizer_189: 1-D VQ codebook lookup. x: [16,1,512,512] fp32 (N=4,194,304
// scalars; C=D=1 so transposes are no-ops), weight: [128,1].
//
// Reference model (NumPy fp32, per-op rounding, NO fma — verified, absmax 0.0):
//   dist_k = fl( fl( fl(x*x) + fl(w_k*w_k) ) - fl( fl(2x) * w_k ) )
//   idx    = np.argmin(dist) — first ORIGINAL index wins ties
//   out    = w[idx]
//
// Round-8: minimal-node + minimal-work configuration. Rounds 0-3 established
// that total time fits: fixed harness resets (~73 us: one 268 MB ws-poison
// fill at ~44 us + dozens of small reset nodes) + our kernel (~8-13 us).
// So: ONE kernel launch (round 3's extra build kernel cost ~+6 us of node/
// serialization), with the cheapest verified per-element body (round 2/3):
//   bucketize (4 VALU) -> 1 LUT read -> 8 parallel b32 candidate reads
//   (2 dependent LDS stages/element), and the cheap per-block LUT build
//   (round-3 vq_build: 4 buckets/thread, ONE ladder pair + incremental
//   walks ~= 1 us/block — NOT round-2's per-bucket double ladder).
//
// Window correctness (rigorous): with |x|<=5.5, |w|<=3.5 the fp32 distance
// errs by eta <= ~9e-6, so any codeword that can win the computed argmin
// satisfies |x-w| <= |x-w*| + sqrt(2*eta) <= |x-w*| + 6.3e-3. For x in [L,R]
// with outside brackets wa<=L, wb>=R, winners' VALUES lie in [wa-d, wb+d].
// Build uses DELTA=1.25e-2 (2x margin) and L,R padded +-1.5 buckets (absorbs
// query-side fp rounding of the bucket map). Evaluated set = [s0, max(s0+8,e0))
// is a SUPERSET of all global minima; extra candidates are harmless (exact
// ties resolved by the si[] fixup, matching np.argmin's first-index rule).
// This exact window/build logic passed absmax=0.0 in rounds 2 AND 3.
//
// CRITICAL (round 1/2 lesson): device default -ffp-contract fuses mul into
// add/sub -> fma, breaking bit-exactness. Keep pragma + opaque asm barriers
// on every product (x*x, w*w, 2x*w).

constexpr int K     = 128;
constexpr int NB    = 1024;   // LUT buckets (keeps windows tight, tail rare)
constexpr int EPT   = 8;
constexpr int BLOCK = 256;

#define DELTA 0.0125f

__global__ __launch_bounds__(BLOCK) void vq_kernel(const float* __restrict__ x,
                                                   const float* __restrict__ w,
                                                   float* __restrict__ out,
                                                   long n, int kk) {
#pragma clang fp contract(off)
    __shared__ float wraw[K];
    __shared__ float sv[K];      // sorted values asc (inf-padded)
    __shared__ int   si[K];      // original index per sorted pos
    __shared__ int   lut[NB];    // packed: s0 | (e0 << 8)

    const int t = threadIdx.x;
    if (t < K) {
        wraw[t] = (t < kk) ? w[t] : __builtin_inff();
        sv[t]   = __builtin_inff();                  // pad slots
        si[t]   = 0x7fffffff;
    }
    __syncthreads();
    if (t < kk) {
        // Stable O(K) rank sort: rank = #{strictly less} + #{equal, earlier}.
        // Inner reads are wave-uniform (loop counter) -> LDS broadcast.
        float v = wraw[t];
        int rank = 0;
        for (int j = 0; j < kk; ++j) {
            float u = wraw[j];
            rank += (u < v) || (u == v && j < t);
        }
        sv[rank] = v;
        si[rank] = t;
    }
    __syncthreads();

    const float lo    = sv[0];
    const float hi    = sv[kk - 1];
    const float range = hi - lo;
    const float scale = (range > 0.f) ? (float)NB / range : 0.f;
    const float binv  = (range > 0.f) ? range / (float)NB : 0.f;
    const int   sMax  = (kk > 8 ? kk : 8) - 8;

    // ---- LUT build (cheap, round-3 form): 4 consecutive buckets/thread.
    // Ladder ONCE for the first bucket, then incremental forward walks
    // (bucket edges are monotone in b).
    {
        const int b0 = t * 4;                         // 256 threads x 4 = 1024
        float L0 = lo + ((float)b0 - 1.5f) * binv;    // padded bucket edges
        float R0 = lo + ((float)b0 + 2.5f) * binv;
        int pL = 0, pR = 0;
#pragma unroll
        for (int st = 64; st > 0; st >>= 1)
            if (sv[pL + st - 1] < L0) pL += st;
        if (pL < K && sv[pL] < L0) ++pL;              // exact #{sv < L0}
#pragma unroll
        for (int st = 64; st > 0; st >>= 1)
            if (sv[pR + st - 1] < R0) pR += st;
        if (pR < K && sv[pR] < R0) ++pR;              // exact #{sv < R0}

        for (int j = 0; j < 4; ++j) {
            int b = b0 + j;
            float Lb = lo + ((float)b - 1.5f) * binv;
            float Rb = lo + ((float)b + 2.5f) * binv;
            while (pL < kk && sv[pL] < Lb) ++pL;      // exact #{sv < Lb}
            while (pR < kk && sv[pR] < Rb) ++pR;      // exact #{sv < Rb}

            float wa  = sv[pL > 0 ? pL - 1 : 0];      // bracket below (finite)
            float wb  = sv[pR < kk ? pR : kk - 1];    // bracket above (finite)
            float tlo = wa - DELTA;
            float thi = wb + DELTA;

            int s0 = pL > 0 ? pL - 1 : 0;             // walk down: #{sv < tlo}
            while (s0 > 0 && sv[s0 - 1] >= tlo) --s0;
            int e0 = pR;                              // walk up: #{sv <= thi}
            while (e0 < kk && sv[e0] <= thi) ++e0;

            if (s0 > sMax) s0 = sMax;                 // 8-wide read stays in [0,K)
            lut[b] = s0 | (e0 << 8);
        }
    }
    __syncthreads();

    long base = ((long)blockIdx.x * BLOCK + t) * (long)EPT;
    if (base + EPT <= n) {
        float4 a  = *(const float4*)(x + base);
        float4 b4 = *(const float4*)(x + base + 4);
        float xs[EPT] = {a.x, a.y, a.z, a.w, b4.x, b4.y, b4.z, b4.w};
        float res[EPT];
#pragma unroll
        for (int e = 0; e < EPT; ++e) {
            float xv = xs[e];
            float x2 = xv * xv;            // fl(x*x)
            asm volatile("" : "+v"(x2));   // block fma(x,x,w2)
            float tx = xv + xv;            // fl(2x), exact

            // Bucketize (fp rounding here is absorbed by build-side padding).
            float fi = (xv - lo) * scale;
            int idx = (int)fi;
            idx = idx < 0 ? 0 : (idx > NB - 1 ? NB - 1 : idx);
            int pk = lut[idx];
            int s  = pk & 0xff;
            int en = pk >> 8;

            float best = __builtin_inff();
            float bw   = 0.0f;
            unsigned tie = 0u;
#pragma unroll
            for (int c = 0; c < 8; ++c) {
                float wv = sv[s + c];
                float w2 = wv * wv;             // fl(w*w)
                asm volatile("" : "+v"(w2));    // keep standalone product
                float sum  = x2 + w2;           // fl(x^2 + w^2)
                float prod = tx * wv;           // fl(2x * w)
                asm volatile("" : "+v"(prod));  // block fma fusion into sub
                float d = sum - prod;           // fl(sum - prod)
                bool lt = d < best;
                tie |= (d == best) ? 1u : 0u;
                best = lt ? d : best;
                bw   = lt ? wv : bw;
            }
            // Rare: window wider than 8 (clustered codewords) — finish it.
            if (__builtin_expect(en > s + 8, 0)) {
                for (int j = s + 8; j < en; ++j) {
                    float wv = sv[j];
                    float w2 = wv * wv;
                    asm volatile("" : "+v"(w2));
                    float sum  = x2 + w2;
                    float prod = tx * wv;
                    asm volatile("" : "+v"(prod));
                    float d = sum - prod;
                    bool lt = d < best;
                    tie |= (d == best) ? 1u : 0u;
                    best = lt ? d : best;
                    bw   = lt ? wv : bw;
                }
            }
            res[e] = bw;
            // Rare exact-tie fixup: np.argmin keeps smallest ORIGINAL index.
            if (__builtin_expect(tie != 0u, 0)) {
                int hiEnd = en > s + 8 ? en : s + 8;
                float bb = __builtin_inff(), bwv = 0.0f;
                int bi = 0x7fffffff;
                for (int j = s; j < hiEnd; ++j) {
                    float wv = sv[j];
                    float w2 = wv * wv;
                    asm volatile("" : "+v"(w2));
                    float sum  = x2 + w2;
                    float prod = tx * wv;
                    asm volatile("" : "+v"(prod));
                    float d = sum - prod;
                    int oi = si[j];
                    if (d < bb || (d == bb && oi < bi)) { bb = d; bi = oi; bwv = wv; }
                }
                res[e] = bwv;
            }
        }
        *(float4*)(out + base)     = make_float4(res[0], res[1], res[2], res[3]);
        *(float4*)(out + base + 4) = make_float4(res[4], res[5], res[6], res[7]);
    } else {
        // Tail (not hit for N=4,194,304): exact brute force over kk entries.
        for (long i = base; i < n; ++i) {
            float xv = x[i];
            float x2 = xv * xv;
            asm volatile("" : "+v"(x2));
            float tx = xv + xv;
            float bb = __builtin_inff(), bwv = 0.0f;
            int bi = 0x7fffffff;
            for (int p0 = 0; p0 < kk; ++p0) {
                float wv = sv[p0];
                float w2 = wv * wv;
                asm volatile("" : "+v"(w2));
                float sum  = x2 + w2;
                float prod = tx * wv;
                asm volatile("" : "+v"(prod));
                float d = sum - prod;
                int oi = si[p0];
                if (d < bb || (d == bb && oi < bi)) { bb = d; bi = oi; bwv = wv; }
            }
            out[i] = bwv;
        }
    }
}

extern "C" void kernel_launch(void* const* d_in, const int* in_sizes, int n_in,
                              void* d_out, int out_size, void* d_ws, size_t ws_size,
                              hipStream_t stream) {
    const float* x = (const float*)d_in[0];
    const float* w = (const float*)d_in[1];
    float* out     = (float*)d_out;
    long n = (long)in_sizes[0];
    int  kk = in_sizes[1] < K ? in_sizes[1] : K;

    long threads_needed = (n + EPT - 1) / EPT;
    long grid = (threads_needed + BLOCK - 1) / BLOCK;
    vq_kernel<<<(int)grid, BLOCK, 0, stream>>>(x, w, out, n, kk);
}

// Round 5
// 80.114 us; speedup vs baseline: 1.1392x; 1.1392x over previous
//
#include <hip/hip_runtime.h>

// Quantizer_189: 1-D VQ codebook lookup. x: [16,1,512,512] fp32 (N=4,194,304
// scalars; C=D=1 so transposes are no-ops), weight: [128,1].
//
// Reference model (NumPy fp32, per-op rounding, NO fma — verified round 3,
// absmax == 0.0):
//   dist_k = fl( fl( fl(x*x) + fl(w_k*w_k) ) - fl( fl(2x) * w_k ) )
//   idx    = np.argmin(dist) — first ORIGINAL index wins ties
//   out    = w[idx]
//
// FINAL (round-9 revert): this is the round-0 kernel, the best of six
// measured structural variants (81.7 us vs 84.9-91.3 for all others).
// Session conclusion: total time = fixed harness resets (~74 us: one 268 MB
// workspace-poison fill @ ~44 us + output/input restore + small reset nodes)
// + this kernel (~8 us vs a 5.3 us HBM floor for 33.5 MB of traffic).
// Attempts that failed to beat it (all absmax 0.0, all within or worse than
// noise): conflict-free Eytzinger search tables (+3), per-block bucket-LUT
// (+9), split build/main kernels (+8), cheap-build LUT (+10). The per-element
// body is NOT the limiter; the LUT build in any form costs more than the
// 3 LDS ops/element it saves.
//
// Algorithm: sort codebook per block, binary-search insertion point,
// evaluate the EXACT reference fp32 distance on the 8 sorted candidates
// [pos-4, pos+3]. Rounding noise in the expansion is <= ~7e-7*x^2, so a
// non-window entry can win only if >=4 codebook entries pack within ~4e-3 —
// negligible for 128 N(0,1) draws. Ties in the fp32 dist are broken by
// original index via a rare predicated branch (matches np.argmin).
//
// CRITICAL (round 1/2 lesson): device default -ffp-contract fuses mul into
// sub -> fma, breaking bit-exactness. Keep pragma + opaque asm barriers on
// every product.

constexpr int K     = 128;
constexpr int EPT   = 8;
constexpr int BLOCK = 256;

__global__ __launch_bounds__(BLOCK) void vq_kernel(const float* __restrict__ x,
                                                   const float* __restrict__ w,
                                                   float* __restrict__ out,
                                                   long n, int kk) {
#pragma clang fp contract(off)
    __shared__ float  wraw[K];  // original-order codebook
    __shared__ float  sv[K];    // sorted values (ascending, stable by orig idx)
    __shared__ float2 wp[K];    // (w, fl(w*w)) in sorted order
    __shared__ int    si[K];    // original index per sorted pos

    const int t = threadIdx.x;
    if (t < K) {
        wraw[t] = (t < kk) ? w[t] : __builtin_inff();
        sv[t]   = __builtin_inff();                       // pad slots
        wp[t]   = make_float2(__builtin_inff(), __builtin_inff());
        si[t]   = 0x7fffffff;
    }
    __syncthreads();
    if (t < kk) {
        // Stable O(K) rank sort per thread: rank = #{strictly less} + #{equal, earlier}.
        float v = wraw[t];
        int rank = 0;
        for (int j = 0; j < kk; ++j) {
            float u = wraw[j];
            rank += (u < v) || (u == v && j < t);
        }
        float v2 = v * v;                  // fl(w*w)
        asm volatile("" : "+v"(v2));       // keep it a standalone product
        sv[rank] = v;
        wp[rank] = make_float2(v, v2);
        si[rank] = t;
    }
    __syncthreads();

    // First 3 search levels from registers (block-uniform values).
    const float m1  = sv[63];
    const float m2a = sv[31],  m2b = sv[95];
    const float m3a = sv[15],  m3b = sv[47], m3c = sv[79], m3d = sv[111];

    long base = ((long)blockIdx.x * BLOCK + t) * (long)EPT;
    if (base + EPT <= n) {
        float4 a = *(const float4*)(x + base);
        float4 b = *(const float4*)(x + base + 4);
        float xs[EPT] = {a.x, a.y, a.z, a.w, b.x, b.y, b.z, b.w};
        float res[EPT];
#pragma unroll
        for (int e = 0; e < EPT; ++e) {
            float xv = xs[e];
            float x2 = xv * xv;            // fl(x*x)
            asm volatile("" : "+v"(x2));   // block fma(x,x,w2)
            float tx = xv + xv;            // fl(2x), exact

            // Branchless lower_bound: pos = #{sv < xv}. Levels 64/32/16 from
            // registers, 8/4/2/1 from LDS.
            int pos = (m1 < xv) ? 64 : 0;
            float m2 = (pos & 64) ? m2b : m2a;
            pos += (m2 < xv) ? 32 : 0;
            float m3lo = (pos & 32) ? m3b : m3a;
            float m3hi = (pos & 32) ? m3d : m3c;
            float m3   = (pos & 64) ? m3hi : m3lo;
            pos += (m3 < xv) ? 16 : 0;
#pragma unroll
            for (int step = 8; step > 0; step >>= 1)
                pos += (sv[pos + step - 1] < xv) ? step : 0;

            // Candidate window [pos-4, pos+3], clamped.
            int s = pos - 4;
            int smax = (kk > 8 ? kk : 8) - 8;
            s = s < 0 ? 0 : (s > smax ? smax : s);

            float best = __builtin_inff();
            int bestPos = s;
            float bw = 0.0f;
#pragma unroll
            for (int c = 0; c < 8; ++c) {
                float2 p = wp[s + c];
                float sum  = x2 + p.y;          // fl(x^2 + w^2)
                float prod = tx * p.x;          // fl(2x * w)
                asm volatile("" : "+v"(prod));  // block fma fusion into sub
                float d = sum - prod;           // fl(sum - prod)
                if (d < best) {
                    best = d; bestPos = s + c; bw = p.x;
                } else if (d == best) {
                    // Exact fp32-dist tie: np.argmin keeps smallest ORIGINAL index.
                    if (si[s + c] < si[bestPos]) { bestPos = s + c; bw = p.x; }
                }
            }
            res[e] = bw;
        }
        *(float4*)(out + base)     = make_float4(res[0], res[1], res[2], res[3]);
        *(float4*)(out + base + 4) = make_float4(res[4], res[5], res[6], res[7]);
    } else {
        // Tail (not hit for N=4,194,304): exact brute force over kk entries.
        for (long i = base; i < n; ++i) {
            float xv = x[i];
            float x2 = xv * xv;
            asm volatile("" : "+v"(x2));
            float tx = xv + xv;
            float best = __builtin_inff(), bwv = 0.0f;
            int bestIdx = 0x7fffffff;
            for (int p0 = 0; p0 < kk; ++p0) {
                float2 p = wp[p0];
                float sum  = x2 + p.y;
                float prod = tx * p.x;
                asm volatile("" : "+v"(prod));
                float d = sum - prod;
                if (d < best || (d == best && si[p0] < bestIdx)) {
                    best = d; bwv = p.x; bestIdx = si[p0];
                }
            }
            out[i] = bwv;
        }
    }
}

extern "C" void kernel_launch(void* const* d_in, const int* in_sizes, int n_in,
                              void* d_out, int out_size, void* d_ws, size_t ws_size,
                              hipStream_t stream) {
    const float* x = (const float*)d_in[0];
    const float* w = (const float*)d_in[1];
    float* out     = (float*)d_out;
    long n = (long)in_sizes[0];
    int  kk = in_sizes[1] < K ? in_sizes[1] : K;

    long threads_needed = (n + EPT - 1) / EPT;
    long grid = (threads_needed + BLOCK - 1) / BLOCK;
    vq_kernel<<<(int)grid, BLOCK, 0, stream>>>(x, w, out, n, kk);
}